// Round 2
// baseline (2525.150 us; speedup 1.0000x reference)
//
#include <hip/hip_runtime.h>
#include <hip/hip_bf16.h>

// Problem constants
#define EMBED 1024
#define NH 16
#define HD 64
#define TSEQ 1024
#define SSEQ 1024
#define BATCH 4

// ---------------------------------------------------------------------------
// NT GEMM: C[m,n] = (sum_k A[m,k] * W[n,k] + bias[n]) * (n < scaleN ? scale : 1)
// A selected per 1024-wide column block (q|k|v use different A matrices).
// BM=BN=128, BK=16, 256 threads, 8x8 microtile split into 4-wide halves:
// thread (ty,tx) owns rows {ty*4..+3, 64+ty*4..+3} x cols {tx*4..+3, 64+tx*4..+3}.
// The 4-float (16B) LDS read stride across 16 lanes gives 2-way bank aliasing
// (free) instead of the 4-way a contiguous 8-wide microtile would cause.
// ---------------------------------------------------------------------------
__global__ __launch_bounds__(256) void gemm_nt(
    const float* __restrict__ A0, const float* __restrict__ A1,
    const float* __restrict__ A2,
    const float* __restrict__ W, const float* __restrict__ bias,
    float* __restrict__ C, int M, int N, int K, int scaleN, float scale)
{
    __shared__ float As[16][128 + 4];   // [k][m]
    __shared__ float Bs[16][128 + 4];   // [k][n]

    const int m0 = blockIdx.y * 128;
    const int n0 = blockIdx.x * 128;
    const float* A = (n0 < EMBED) ? A0 : (n0 < 2 * EMBED ? A1 : A2);

    const int tid = threadIdx.x;
    const int ty = tid >> 4;          // 0..15
    const int tx = tid & 15;          // 0..15
    const int lr = tid >> 1;          // 0..127: tile row for loads
    const int lk = (tid & 1) * 8;     // k offset {0,8}

    const float* Ap = A + (size_t)(m0 + lr) * K + lk;
    const float* Wp = W + (size_t)(n0 + lr) * K + lk;

    float acc[8][8] = {};

    for (int k0 = 0; k0 < K; k0 += 16) {
        // stage global->reg before the barrier (overlaps prior compute)
        const float4 a0 = *(const float4*)(Ap + k0);
        const float4 a1 = *(const float4*)(Ap + k0 + 4);
        const float4 b0 = *(const float4*)(Wp + k0);
        const float4 b1 = *(const float4*)(Wp + k0 + 4);
        __syncthreads();   // prev iteration's compute done before overwrite
        As[lk + 0][lr] = a0.x; As[lk + 1][lr] = a0.y;
        As[lk + 2][lr] = a0.z; As[lk + 3][lr] = a0.w;
        As[lk + 4][lr] = a1.x; As[lk + 5][lr] = a1.y;
        As[lk + 6][lr] = a1.z; As[lk + 7][lr] = a1.w;
        Bs[lk + 0][lr] = b0.x; Bs[lk + 1][lr] = b0.y;
        Bs[lk + 2][lr] = b0.z; Bs[lk + 3][lr] = b0.w;
        Bs[lk + 4][lr] = b1.x; Bs[lk + 5][lr] = b1.y;
        Bs[lk + 6][lr] = b1.z; Bs[lk + 7][lr] = b1.w;
        __syncthreads();

        #pragma unroll
        for (int kk = 0; kk < 16; ++kk) {
            const float4 av0 = *(const float4*)&As[kk][ty * 4];
            const float4 av1 = *(const float4*)&As[kk][64 + ty * 4];
            const float4 bv0 = *(const float4*)&Bs[kk][tx * 4];
            const float4 bv1 = *(const float4*)&Bs[kk][64 + tx * 4];
            const float ar[8] = {av0.x, av0.y, av0.z, av0.w,
                                 av1.x, av1.y, av1.z, av1.w};
            const float br[8] = {bv0.x, bv0.y, bv0.z, bv0.w,
                                 bv1.x, bv1.y, bv1.z, bv1.w};
            #pragma unroll
            for (int i = 0; i < 8; ++i)
                #pragma unroll
                for (int j = 0; j < 8; ++j)
                    acc[i][j] += ar[i] * br[j];
        }
    }

    // epilogue: bias + optional scale, float4 stores (16 lanes x 16B contiguous)
    #pragma unroll
    for (int ih = 0; ih < 2; ++ih) {
        #pragma unroll
        for (int i = 0; i < 4; ++i) {
            const int m = m0 + ih * 64 + ty * 4 + i;
            #pragma unroll
            for (int jh = 0; jh < 2; ++jh) {
                const int n = n0 + jh * 64 + tx * 4;
                const float s = (n < scaleN) ? scale : 1.0f;
                float4 r;
                r.x = (acc[ih * 4 + i][jh * 4 + 0] + bias[n + 0]) * s;
                r.y = (acc[ih * 4 + i][jh * 4 + 1] + bias[n + 1]) * s;
                r.z = (acc[ih * 4 + i][jh * 4 + 2] + bias[n + 2]) * s;
                r.w = (acc[ih * 4 + i][jh * 4 + 3] + bias[n + 3]) * s;
                *(float4*)&C[(size_t)m * N + n] = r;
            }
        }
    }
}

// ---------------------------------------------------------------------------
// Fused attention: block = (b, h, 32 q-rows). Two-pass softmax over S.
// qkv layout: [T*B rows][3*EMBED], row = t*B+b; q at col h*64, k at 1024+h*64,
// v at 2048+h*64. Thread map: ty=tid/8 (q-row 0..31), tx=tid&7.
//   scores:  thread owns s-slice {tx*8..tx*8+7}; K in LDS d-major (float4 reads)
//   PV:      P staged in LDS; thread owns d-slice {tx*8..tx*8+7}
// avg_weights accumulated with atomicAdd(p/H) into pre-zeroed d_out region.
// ---------------------------------------------------------------------------
#define TT 32
#define ST 64
__global__ __launch_bounds__(256) void attn_fused(
    const float* __restrict__ qkv,
    const int* __restrict__ pad,      // [B,S], nonzero = padded
    const float* __restrict__ amask,  // [T,S]
    float* __restrict__ attn_out,     // [T*B, EMBED]
    float* __restrict__ avg)          // [B,T,S], pre-zeroed
{
    __shared__ float Qs[TT][HD + 4];
    __shared__ float Kt[HD][ST + 4];  // transposed: [d][s]
    __shared__ float Vs[ST][HD + 4];  // natural: [s][d]
    __shared__ float Ps[TT][ST + 4];

    const int ntb = TSEQ / TT;
    const int tb = blockIdx.x % ntb;
    const int bh = blockIdx.x / ntb;
    const int b = bh % BATCH;
    const int h = bh / BATCH;
    const int t0 = tb * TT;
    const int tid = threadIdx.x;
    const int ty = tid >> 3;  // 0..31
    const int tx = tid & 7;   // 0..7

    // load Q tile (scale already applied in projection)
    {
        const int r = tid >> 3;
        const int d = (tid & 7) * 8;
        const float* qp = qkv + (size_t)((t0 + r) * BATCH + b) * (3 * EMBED) + h * HD + d;
        *(float4*)&Qs[r][d]     = *(const float4*)qp;
        *(float4*)&Qs[r][d + 4] = *(const float4*)(qp + 4);
    }

    float m_run = -1e30f, l_run = 0.f;
    const int nst = SSEQ / ST;

    // ---------------- pass 1: row max & sum ----------------
    for (int st = 0; st < nst; ++st) {
        const int s0 = st * ST;
        __syncthreads();
        #pragma unroll
        for (int i = 0; i < 4; ++i) {
            const int s = (tid >> 4) + i * 16;
            const int d4 = (tid & 15) * 4;
            float4 kv = *(const float4*)(qkv + (size_t)((s0 + s) * BATCH + b) * (3 * EMBED)
                                         + EMBED + h * HD + d4);
            Kt[d4 + 0][s] = kv.x; Kt[d4 + 1][s] = kv.y;
            Kt[d4 + 2][s] = kv.z; Kt[d4 + 3][s] = kv.w;
        }
        __syncthreads();

        float sc[8] = {0, 0, 0, 0, 0, 0, 0, 0};
        #pragma unroll
        for (int d = 0; d < HD; ++d) {
            const float qd = Qs[ty][d];
            const float4* kp = (const float4*)&Kt[d][tx * 8];
            const float4 k0 = kp[0], k1 = kp[1];
            sc[0] += qd * k0.x; sc[1] += qd * k0.y;
            sc[2] += qd * k0.z; sc[3] += qd * k0.w;
            sc[4] += qd * k1.x; sc[5] += qd * k1.y;
            sc[6] += qd * k1.z; sc[7] += qd * k1.w;
        }

        const float4* am = (const float4*)(amask + (size_t)(t0 + ty) * SSEQ + s0 + tx * 8);
        const float4 a0 = am[0], a1 = am[1];
        const int4* pp = (const int4*)(pad + b * SSEQ + s0 + tx * 8);
        const int4 p0 = pp[0], p1 = pp[1];
        const float af[8] = {a0.x, a0.y, a0.z, a0.w, a1.x, a1.y, a1.z, a1.w};
        const int pf[8] = {p0.x, p0.y, p0.z, p0.w, p1.x, p1.y, p1.z, p1.w};
        float sf[8];
        #pragma unroll
        for (int j = 0; j < 8; ++j)
            sf[j] = sc[j] + af[j] + (pf[j] ? -1e30f : 0.f);

        float tmax = sf[0];
        #pragma unroll
        for (int j = 1; j < 8; ++j) tmax = fmaxf(tmax, sf[j]);
        const float mnew = fmaxf(m_run, tmax);
        float lsum = 0.f;
        #pragma unroll
        for (int j = 0; j < 8; ++j) lsum += __expf(sf[j] - mnew);
        l_run = l_run * __expf(m_run - mnew) + lsum;
        m_run = mnew;
    }

    // merge (m,l) across the 8 lanes of each q-row (contiguous lanes)
    #pragma unroll
    for (int off = 1; off < 8; off <<= 1) {
        const float mo = __shfl_xor(m_run, off);
        const float lo = __shfl_xor(l_run, off);
        const float mn = fmaxf(m_run, mo);
        l_run = l_run * __expf(m_run - mn) + lo * __expf(mo - mn);
        m_run = mn;
    }
    const float inv_l = 1.0f / l_run;
    const float inv_H = 1.0f / NH;

    float o[8] = {0, 0, 0, 0, 0, 0, 0, 0};

    // ---------------- pass 2: P, avg_weights, PV ----------------
    for (int st = 0; st < nst; ++st) {
        const int s0 = st * ST;
        __syncthreads();
        #pragma unroll
        for (int i = 0; i < 4; ++i) {
            const int s = (tid >> 4) + i * 16;
            const int d4 = (tid & 15) * 4;
            const float* base = qkv + (size_t)((s0 + s) * BATCH + b) * (3 * EMBED) + h * HD + d4;
            float4 kv = *(const float4*)(base + EMBED);
            float4 vv = *(const float4*)(base + 2 * EMBED);
            Kt[d4 + 0][s] = kv.x; Kt[d4 + 1][s] = kv.y;
            Kt[d4 + 2][s] = kv.z; Kt[d4 + 3][s] = kv.w;
            *(float4*)&Vs[s][d4] = vv;
        }
        __syncthreads();

        float sc[8] = {0, 0, 0, 0, 0, 0, 0, 0};
        #pragma unroll
        for (int d = 0; d < HD; ++d) {
            const float qd = Qs[ty][d];
            const float4* kp = (const float4*)&Kt[d][tx * 8];
            const float4 k0 = kp[0], k1 = kp[1];
            sc[0] += qd * k0.x; sc[1] += qd * k0.y;
            sc[2] += qd * k0.z; sc[3] += qd * k0.w;
            sc[4] += qd * k1.x; sc[5] += qd * k1.y;
            sc[6] += qd * k1.z; sc[7] += qd * k1.w;
        }

        const float4* am = (const float4*)(amask + (size_t)(t0 + ty) * SSEQ + s0 + tx * 8);
        const float4 a0 = am[0], a1 = am[1];
        const int4* pp = (const int4*)(pad + b * SSEQ + s0 + tx * 8);
        const int4 p0 = pp[0], p1 = pp[1];
        const float af[8] = {a0.x, a0.y, a0.z, a0.w, a1.x, a1.y, a1.z, a1.w};
        const int pf[8] = {p0.x, p0.y, p0.z, p0.w, p1.x, p1.y, p1.z, p1.w};
        float p[8];
        #pragma unroll
        for (int j = 0; j < 8; ++j) {
            const float sf = sc[j] + af[j] + (pf[j] ? -1e30f : 0.f);
            p[j] = __expf(sf - m_run) * inv_l;
        }

        *(float4*)&Ps[ty][tx * 8]     = make_float4(p[0], p[1], p[2], p[3]);
        *(float4*)&Ps[ty][tx * 8 + 4] = make_float4(p[4], p[5], p[6], p[7]);

        float* ap = avg + ((size_t)b * TSEQ + (t0 + ty)) * SSEQ + s0 + tx * 8;
        #pragma unroll
        for (int j = 0; j < 8; ++j) atomicAdd(ap + j, p[j] * inv_H);

        __syncthreads();

        // PV: thread owns d-slice tx*8..tx*8+7 for its row ty
        #pragma unroll
        for (int s = 0; s < ST; ++s) {
            const float pv = Ps[ty][s];
            const float4* vp = (const float4*)&Vs[s][tx * 8];
            const float4 v0 = vp[0], v1 = vp[1];
            o[0] += pv * v0.x; o[1] += pv * v0.y;
            o[2] += pv * v0.z; o[3] += pv * v0.w;
            o[4] += pv * v1.x; o[5] += pv * v1.y;
            o[6] += pv * v1.z; o[7] += pv * v1.w;
        }
    }

    float* op = attn_out + (size_t)((t0 + ty) * BATCH + b) * EMBED + h * HD + tx * 8;
    *(float4*)op       = make_float4(o[0], o[1], o[2], o[3]);
    *(float4*)(op + 4) = make_float4(o[4], o[5], o[6], o[7]);
}

// ---------------------------------------------------------------------------
extern "C" void kernel_launch(void* const* d_in, const int* in_sizes, int n_in,
                              void* d_out, int out_size, void* d_ws, size_t ws_size,
                              hipStream_t stream) {
    const float* query = (const float*)d_in[0];   // [T,B,E]
    const float* key   = (const float*)d_in[1];   // [S,B,E]
    const float* value = (const float*)d_in[2];   // [S,B,E]
    const int*   pad   = (const int*)d_in[3];     // [B,S]
    const float* amask = (const float*)d_in[4];   // [T,S]
    const float* wqkv  = (const float*)d_in[5];   // [3E,E]
    const float* bqkv  = (const float*)d_in[6];   // [3E]
    const float* wout  = (const float*)d_in[7];   // [E,E]
    const float* bout  = (const float*)d_in[8];   // [E]

    float* out = (float*)d_out;                          // [T,B,E]
    float* avg = out + (size_t)TSEQ * BATCH * EMBED;     // [B,T,S]

    float* qkv  = (float*)d_ws;                          // [T*B, 3E] = 48 MB
    float* attn = qkv + (size_t)(TSEQ * BATCH) * (3 * EMBED);  // [T*B, E] = 16 MB

    const int M = TSEQ * BATCH;  // 4096
    const float scaling = 0.125f;  // HD^-0.5

    dim3 g1(3 * EMBED / 128, M / 128);
    gemm_nt<<<g1, 256, 0, stream>>>(query, key, value, wqkv, bqkv, qkv,
                                    M, 3 * EMBED, EMBED, EMBED, scaling);

    hipMemsetAsync(avg, 0, (size_t)BATCH * TSEQ * SSEQ * sizeof(float), stream);

    dim3 g2(BATCH * NH * (TSEQ / TT));
    attn_fused<<<g2, 256, 0, stream>>>(qkv, pad, amask, attn, avg);

    dim3 g3(EMBED / 128, M / 128);
    gemm_nt<<<g3, 256, 0, stream>>>(attn, attn, attn, wout, bout, out,
                                    M, EMBED, EMBED, 0, 1.f);
}

// Round 3
// 1397.879 us; speedup vs baseline: 1.8064x; 1.8064x over previous
//
#include <hip/hip_runtime.h>
#include <hip/hip_bf16.h>

// Problem constants
#define EMBED 1024
#define NH 16
#define HD 64
#define TSEQ 1024
#define SSEQ 1024
#define BATCH 4
#define AVGN ((size_t)BATCH * TSEQ * SSEQ)   // elements in avg_weights

// ---------------------------------------------------------------------------
// NT GEMM: C[m,n] = (sum_k A[m,k] * W[n,k] + bias[n]) * (n < scaleN ? scale : 1)
// A selected per 1024-wide column block (q|k|v use different A matrices).
// BM=BN=128, BK=16, 256 threads, 8x8 microtile split into 4-wide halves.
// ---------------------------------------------------------------------------
__global__ __launch_bounds__(256) void gemm_nt(
    const float* __restrict__ A0, const float* __restrict__ A1,
    const float* __restrict__ A2,
    const float* __restrict__ W, const float* __restrict__ bias,
    float* __restrict__ C, int M, int N, int K, int scaleN, float scale)
{
    __shared__ float As[16][128 + 4];   // [k][m]
    __shared__ float Bs[16][128 + 4];   // [k][n]

    const int m0 = blockIdx.y * 128;
    const int n0 = blockIdx.x * 128;
    const float* A = (n0 < EMBED) ? A0 : (n0 < 2 * EMBED ? A1 : A2);

    const int tid = threadIdx.x;
    const int ty = tid >> 4;          // 0..15
    const int tx = tid & 15;          // 0..15
    const int lr = tid >> 1;          // 0..127: tile row for loads
    const int lk = (tid & 1) * 8;     // k offset {0,8}

    const float* Ap = A + (size_t)(m0 + lr) * K + lk;
    const float* Wp = W + (size_t)(n0 + lr) * K + lk;

    float acc[8][8] = {};

    for (int k0 = 0; k0 < K; k0 += 16) {
        const float4 a0 = *(const float4*)(Ap + k0);
        const float4 a1 = *(const float4*)(Ap + k0 + 4);
        const float4 b0 = *(const float4*)(Wp + k0);
        const float4 b1 = *(const float4*)(Wp + k0 + 4);
        __syncthreads();
        As[lk + 0][lr] = a0.x; As[lk + 1][lr] = a0.y;
        As[lk + 2][lr] = a0.z; As[lk + 3][lr] = a0.w;
        As[lk + 4][lr] = a1.x; As[lk + 5][lr] = a1.y;
        As[lk + 6][lr] = a1.z; As[lk + 7][lr] = a1.w;
        Bs[lk + 0][lr] = b0.x; Bs[lk + 1][lr] = b0.y;
        Bs[lk + 2][lr] = b0.z; Bs[lk + 3][lr] = b0.w;
        Bs[lk + 4][lr] = b1.x; Bs[lk + 5][lr] = b1.y;
        Bs[lk + 6][lr] = b1.z; Bs[lk + 7][lr] = b1.w;
        __syncthreads();

        #pragma unroll
        for (int kk = 0; kk < 16; ++kk) {
            const float4 av0 = *(const float4*)&As[kk][ty * 4];
            const float4 av1 = *(const float4*)&As[kk][64 + ty * 4];
            const float4 bv0 = *(const float4*)&Bs[kk][tx * 4];
            const float4 bv1 = *(const float4*)&Bs[kk][64 + tx * 4];
            const float ar[8] = {av0.x, av0.y, av0.z, av0.w,
                                 av1.x, av1.y, av1.z, av1.w};
            const float br[8] = {bv0.x, bv0.y, bv0.z, bv0.w,
                                 bv1.x, bv1.y, bv1.z, bv1.w};
            #pragma unroll
            for (int i = 0; i < 8; ++i)
                #pragma unroll
                for (int j = 0; j < 8; ++j)
                    acc[i][j] += ar[i] * br[j];
        }
    }

    #pragma unroll
    for (int ih = 0; ih < 2; ++ih) {
        #pragma unroll
        for (int i = 0; i < 4; ++i) {
            const int m = m0 + ih * 64 + ty * 4 + i;
            #pragma unroll
            for (int jh = 0; jh < 2; ++jh) {
                const int n = n0 + jh * 64 + tx * 4;
                const float s = (n < scaleN) ? scale : 1.0f;
                float4 r;
                r.x = (acc[ih * 4 + i][jh * 4 + 0] + bias[n + 0]) * s;
                r.y = (acc[ih * 4 + i][jh * 4 + 1] + bias[n + 1]) * s;
                r.z = (acc[ih * 4 + i][jh * 4 + 2] + bias[n + 2]) * s;
                r.w = (acc[ih * 4 + i][jh * 4 + 3] + bias[n + 3]) * s;
                *(float4*)&C[(size_t)m * N + n] = r;
            }
        }
    }
}

// ---------------------------------------------------------------------------
// Fused attention, atomic-free avg path.
// Block = (b, t-tile of 32, head-group g). Loops HG heads sequentially.
// Each block OWNS avg rows [b, t0:t0+32, :] for its group's partial buffer:
// first head writes p/H, later heads do plain read-add-write (same thread
// touches the same elements -> program order, no race, no atomics).
// Group 0 accumulates directly into avg (d_out); groups 1.. into ws partials.
// ---------------------------------------------------------------------------
#define TT 32
#define ST 64
__global__ __launch_bounds__(256) void attn_fused(
    const float* __restrict__ qkv,
    const int* __restrict__ pad,      // [B,S], nonzero = padded
    const float* __restrict__ amask,  // [T,S]
    float* __restrict__ attn_out,     // [T*B, EMBED]
    float* __restrict__ avg,          // [B,T,S] (d_out region)
    float* __restrict__ parts,        // (G-1) partial buffers of AVGN floats
    int HG)                           // heads per group
{
    __shared__ float Qs[TT][HD + 4];
    __shared__ float Kt[HD][ST + 4];  // transposed: [d][s]
    __shared__ float Vs[ST][HD + 4];  // natural: [s][d]
    __shared__ float Ps[TT][ST + 4];

    const int ntb = TSEQ / TT;
    const int tb = blockIdx.x % ntb;
    const int b  = (blockIdx.x / ntb) % BATCH;
    const int g  = blockIdx.x / (ntb * BATCH);
    const int h0 = g * HG;
    const int t0 = tb * TT;
    const int tid = threadIdx.x;
    const int ty = tid >> 3;  // 0..31
    const int tx = tid & 7;   // 0..7

    float* dst = (g == 0) ? avg : parts + (size_t)(g - 1) * AVGN;
    const float inv_H = 1.0f / NH;
    const int nst = SSEQ / ST;

    for (int h = h0; h < h0 + HG; ++h) {
        // load Q tile for this head (scale pre-applied in projection).
        // All prior-head reads of Qs completed before the last pre-PV barrier.
        {
            const int r = tid >> 3;
            const int d = (tid & 7) * 8;
            const float* qp = qkv + (size_t)((t0 + r) * BATCH + b) * (3 * EMBED) + h * HD + d;
            *(float4*)&Qs[r][d]     = *(const float4*)qp;
            *(float4*)&Qs[r][d + 4] = *(const float4*)(qp + 4);
        }

        float m_run = -1e30f, l_run = 0.f;

        // ---------------- pass 1: row max & sum ----------------
        for (int st = 0; st < nst; ++st) {
            const int s0 = st * ST;
            __syncthreads();
            #pragma unroll
            for (int i = 0; i < 4; ++i) {
                const int s = (tid >> 4) + i * 16;
                const int d4 = (tid & 15) * 4;
                float4 kv = *(const float4*)(qkv + (size_t)((s0 + s) * BATCH + b) * (3 * EMBED)
                                             + EMBED + h * HD + d4);
                Kt[d4 + 0][s] = kv.x; Kt[d4 + 1][s] = kv.y;
                Kt[d4 + 2][s] = kv.z; Kt[d4 + 3][s] = kv.w;
            }
            __syncthreads();

            float sc[8] = {0, 0, 0, 0, 0, 0, 0, 0};
            #pragma unroll
            for (int d = 0; d < HD; ++d) {
                const float qd = Qs[ty][d];
                const float4* kp = (const float4*)&Kt[d][tx * 8];
                const float4 k0 = kp[0], k1 = kp[1];
                sc[0] += qd * k0.x; sc[1] += qd * k0.y;
                sc[2] += qd * k0.z; sc[3] += qd * k0.w;
                sc[4] += qd * k1.x; sc[5] += qd * k1.y;
                sc[6] += qd * k1.z; sc[7] += qd * k1.w;
            }

            const float4* am = (const float4*)(amask + (size_t)(t0 + ty) * SSEQ + s0 + tx * 8);
            const float4 a0 = am[0], a1 = am[1];
            const int4* pp = (const int4*)(pad + b * SSEQ + s0 + tx * 8);
            const int4 p0 = pp[0], p1 = pp[1];
            const float af[8] = {a0.x, a0.y, a0.z, a0.w, a1.x, a1.y, a1.z, a1.w};
            const int pf[8] = {p0.x, p0.y, p0.z, p0.w, p1.x, p1.y, p1.z, p1.w};
            float sf[8];
            #pragma unroll
            for (int j = 0; j < 8; ++j)
                sf[j] = sc[j] + af[j] + (pf[j] ? -1e30f : 0.f);

            float tmax = sf[0];
            #pragma unroll
            for (int j = 1; j < 8; ++j) tmax = fmaxf(tmax, sf[j]);
            const float mnew = fmaxf(m_run, tmax);
            float lsum = 0.f;
            #pragma unroll
            for (int j = 0; j < 8; ++j) lsum += __expf(sf[j] - mnew);
            l_run = l_run * __expf(m_run - mnew) + lsum;
            m_run = mnew;
        }

        // merge (m,l) across the 8 lanes of each q-row
        #pragma unroll
        for (int off = 1; off < 8; off <<= 1) {
            const float mo = __shfl_xor(m_run, off);
            const float lo = __shfl_xor(l_run, off);
            const float mn = fmaxf(m_run, mo);
            l_run = l_run * __expf(m_run - mn) + lo * __expf(mo - mn);
            m_run = mn;
        }
        const float inv_l = 1.0f / l_run;

        float o[8] = {0, 0, 0, 0, 0, 0, 0, 0};

        // ---------------- pass 2: P, avg accumulate, PV ----------------
        for (int st = 0; st < nst; ++st) {
            const int s0 = st * ST;
            __syncthreads();
            #pragma unroll
            for (int i = 0; i < 4; ++i) {
                const int s = (tid >> 4) + i * 16;
                const int d4 = (tid & 15) * 4;
                const float* base = qkv + (size_t)((s0 + s) * BATCH + b) * (3 * EMBED) + h * HD + d4;
                float4 kv = *(const float4*)(base + EMBED);
                float4 vv = *(const float4*)(base + 2 * EMBED);
                Kt[d4 + 0][s] = kv.x; Kt[d4 + 1][s] = kv.y;
                Kt[d4 + 2][s] = kv.z; Kt[d4 + 3][s] = kv.w;
                *(float4*)&Vs[s][d4] = vv;
            }
            __syncthreads();

            float sc[8] = {0, 0, 0, 0, 0, 0, 0, 0};
            #pragma unroll
            for (int d = 0; d < HD; ++d) {
                const float qd = Qs[ty][d];
                const float4* kp = (const float4*)&Kt[d][tx * 8];
                const float4 k0 = kp[0], k1 = kp[1];
                sc[0] += qd * k0.x; sc[1] += qd * k0.y;
                sc[2] += qd * k0.z; sc[3] += qd * k0.w;
                sc[4] += qd * k1.x; sc[5] += qd * k1.y;
                sc[6] += qd * k1.z; sc[7] += qd * k1.w;
            }

            const float4* am = (const float4*)(amask + (size_t)(t0 + ty) * SSEQ + s0 + tx * 8);
            const float4 a0 = am[0], a1 = am[1];
            const int4* pp = (const int4*)(pad + b * SSEQ + s0 + tx * 8);
            const int4 p0 = pp[0], p1 = pp[1];
            const float af[8] = {a0.x, a0.y, a0.z, a0.w, a1.x, a1.y, a1.z, a1.w};
            const int pf[8] = {p0.x, p0.y, p0.z, p0.w, p1.x, p1.y, p1.z, p1.w};
            float p[8];
            #pragma unroll
            for (int j = 0; j < 8; ++j) {
                const float sf = sc[j] + af[j] + (pf[j] ? -1e30f : 0.f);
                p[j] = __expf(sf - m_run) * inv_l;
            }

            *(float4*)&Ps[ty][tx * 8]     = make_float4(p[0], p[1], p[2], p[3]);
            *(float4*)&Ps[ty][tx * 8 + 4] = make_float4(p[4], p[5], p[6], p[7]);

            // avg accumulate: this thread owns these 8 elements for all heads
            // of this group -> plain RMW, no atomics.
            float* ap = dst + ((size_t)b * TSEQ + (t0 + ty)) * SSEQ + s0 + tx * 8;
            if (h == h0) {
                *(float4*)ap       = make_float4(p[0] * inv_H, p[1] * inv_H,
                                                 p[2] * inv_H, p[3] * inv_H);
                *(float4*)(ap + 4) = make_float4(p[4] * inv_H, p[5] * inv_H,
                                                 p[6] * inv_H, p[7] * inv_H);
            } else {
                float4 c0 = *(const float4*)ap;
                float4 c1 = *(const float4*)(ap + 4);
                c0.x += p[0] * inv_H; c0.y += p[1] * inv_H;
                c0.z += p[2] * inv_H; c0.w += p[3] * inv_H;
                c1.x += p[4] * inv_H; c1.y += p[5] * inv_H;
                c1.z += p[6] * inv_H; c1.w += p[7] * inv_H;
                *(float4*)ap       = c0;
                *(float4*)(ap + 4) = c1;
            }

            __syncthreads();

            // PV: thread owns d-slice tx*8..tx*8+7 for its row ty
            #pragma unroll
            for (int s = 0; s < ST; ++s) {
                const float pv = Ps[ty][s];
                const float4* vp = (const float4*)&Vs[s][tx * 8];
                const float4 v0 = vp[0], v1 = vp[1];
                o[0] += pv * v0.x; o[1] += pv * v0.y;
                o[2] += pv * v0.z; o[3] += pv * v0.w;
                o[4] += pv * v1.x; o[5] += pv * v1.y;
                o[6] += pv * v1.z; o[7] += pv * v1.w;
            }
        }

        float* op = attn_out + (size_t)((t0 + ty) * BATCH + b) * EMBED + h * HD + tx * 8;
        *(float4*)op       = make_float4(o[0], o[1], o[2], o[3]);
        *(float4*)(op + 4) = make_float4(o[4], o[5], o[6], o[7]);
    }
}

// ---------------------------------------------------------------------------
// avg += sum of partial buffers (only launched when G > 1)
// ---------------------------------------------------------------------------
__global__ __launch_bounds__(256) void reduce_avg(
    float* __restrict__ avg, const float* __restrict__ parts, int nparts)
{
    const size_t n4 = AVGN / 4;
    size_t i = (size_t)blockIdx.x * blockDim.x + threadIdx.x;
    const size_t stride = (size_t)gridDim.x * blockDim.x;
    for (; i < n4; i += stride) {
        float4 a = ((const float4*)avg)[i];
        for (int g = 0; g < nparts; ++g) {
            const float4 p = ((const float4*)(parts + (size_t)g * AVGN))[i];
            a.x += p.x; a.y += p.y; a.z += p.z; a.w += p.w;
        }
        ((float4*)avg)[i] = a;
    }
}

// ---------------------------------------------------------------------------
extern "C" void kernel_launch(void* const* d_in, const int* in_sizes, int n_in,
                              void* d_out, int out_size, void* d_ws, size_t ws_size,
                              hipStream_t stream) {
    const float* query = (const float*)d_in[0];   // [T,B,E]
    const float* key   = (const float*)d_in[1];   // [S,B,E]
    const float* value = (const float*)d_in[2];   // [S,B,E]
    const int*   pad   = (const int*)d_in[3];     // [B,S]
    const float* amask = (const float*)d_in[4];   // [T,S]
    const float* wqkv  = (const float*)d_in[5];   // [3E,E]
    const float* bqkv  = (const float*)d_in[6];   // [3E]
    const float* wout  = (const float*)d_in[7];   // [E,E]
    const float* bout  = (const float*)d_in[8];   // [E]

    float* out = (float*)d_out;                          // [T,B,E]
    float* avg = out + (size_t)TSEQ * BATCH * EMBED;     // [B,T,S]

    float* qkv  = (float*)d_ws;                                   // [T*B, 3E]
    float* attn = qkv + (size_t)(TSEQ * BATCH) * (3 * EMBED);     // [T*B, E]
    float* parts = attn + (size_t)(TSEQ * BATCH) * EMBED;         // (G-1)*AVGN

    const size_t base_bytes = ((size_t)(TSEQ * BATCH) * (3 * EMBED)
                             + (size_t)(TSEQ * BATCH) * EMBED) * sizeof(float);
    // pick head-group count from available scratch (constant per session)
    int G = 1;
    if (ws_size >= base_bytes + 3 * AVGN * sizeof(float)) G = 4;
    else if (ws_size >= base_bytes + 1 * AVGN * sizeof(float)) G = 2;

    const int M = TSEQ * BATCH;  // 4096
    const float scaling = 0.125f;  // HD^-0.5

    dim3 g1(3 * EMBED / 128, M / 128);
    gemm_nt<<<g1, 256, 0, stream>>>(query, key, value, wqkv, bqkv, qkv,
                                    M, 3 * EMBED, EMBED, EMBED, scaling);

    dim3 g2((TSEQ / TT) * BATCH * G);
    attn_fused<<<g2, 256, 0, stream>>>(qkv, pad, amask, attn, avg, parts, NH / G);

    if (G > 1) {
        reduce_avg<<<1024, 256, 0, stream>>>(avg, parts, G - 1);
    }

    dim3 g3(EMBED / 128, M / 128);
    gemm_nt<<<g3, 256, 0, stream>>>(attn, attn, attn, wout, bout, out,
                                    M, EMBED, EMBED, 0, 1.f);
}